// Round 19
// baseline (826.423 us; speedup 1.0000x reference)
//
#include <hip/hip_runtime.h>
#include <hip/hip_bf16.h>

#define NNODES 100000
#define FD 128
#define NEDGES 640000
#define NB 391            // ceil(NNODES/256)
#define NT64 1563         // ceil(NNODES/64): 64-row tiles
#define GX_TWOA 85        // dual-A gemms: 255 blocks, 1/CU (130KB LDS)
#define GX_ONEW 170       // single-A bf16 gemm: 510 blocks, 2/CU (64KB LDS)
#define GX_HEAD 256       // head f32 gemm: 256 blocks, 1/CU (128KB LDS)
#define OFFS_U32 100032   // padded NNODES+1

typedef __bf16 bf16x8 __attribute__((ext_vector_type(8)));
typedef __bf16 bf16x4 __attribute__((ext_vector_type(4)));
typedef float f32x4 __attribute__((ext_vector_type(4)));
typedef unsigned short u16x8 __attribute__((ext_vector_type(8)));

__device__ __forceinline__ bf16x8 cvt8(float4 a, float4 b) {
  bf16x8 r;
  r[0] = (__bf16)a.x; r[1] = (__bf16)a.y; r[2] = (__bf16)a.z; r[3] = (__bf16)a.w;
  r[4] = (__bf16)b.x; r[5] = (__bf16)b.y; r[6] = (__bf16)b.z; r[7] = (__bf16)b.w;
  return r;
}

// async global->LDS, 16B/lane; LDS dest = wave-uniform base + lane*16
__device__ __forceinline__ void gl16(const void* g, void* l) {
  __builtin_amdgcn_global_load_lds(
      (const __attribute__((address_space(1))) unsigned int*)g,
      (__attribute__((address_space(3))) unsigned int*)l, 16, 0, 0);
}

// stage 64-row bf16 tile ROW-MAJOR with XOR-swizzled 16B slots:
// LDS[rl][p] = A[row0+rl][p ^ (rl&7)]  (p = 16B unit 0..15).
// Each gl16 reads 1KB CONTIGUOUS (4 rows x 256B; permutation stays inside
// each row) -> fully-used cache lines. Wave w stages rows 8w..8w+7.
__device__ __forceinline__ void stage_abf(const __bf16* A, long row0, int M,
                                          char* l, int wid, int lane) {
#pragma unroll
  for (int i = 0; i < 2; ++i) {
    const int r0 = wid * 8 + i * 4;       // wave-uniform: 4 rows / instruction
    const int rl = r0 + (lane >> 4);
    long row = row0 + rl;
    if (row > M - 1) row = M - 1;         // clamp; stores guarded in epilogue
    const int slot = (lane & 15) ^ (rl & 7);
    gl16((const char*)(A + row * FD) + slot * 16, l + r0 * 256);
  }
}

// stage 64-row f32 tile row-major (512B rows, 32 slots), same swizzle
__device__ __forceinline__ void stage_a32(const float* A, long row0, int M,
                                          char* l, int wid, int lane) {
#pragma unroll
  for (int i = 0; i < 4; ++i) {
    const int r0 = wid * 8 + i * 2;       // 2 rows / instruction
    const int rl = r0 + (lane >> 5);
    long row = row0 + rl;
    if (row > M - 1) row = M - 1;
    const int slot = (lane & 31) ^ (rl & 7);
    gl16((const char*)(A + row * FD) + slot * 16, l + r0 * 512);
  }
}

// ---- pack all 6 weight matrices f32[128][128] -> bf16 MFMA fragments ----
// frag f = (c*4+kk)*64 + lane; elem j = W[(c*16+(lane&15))][kk*32+(lane>>4)*8+j]
__global__ __launch_bounds__(256) void packw6_k(
    const float* __restrict__ W0, const float* __restrict__ W1,
    const float* __restrict__ W2, const float* __restrict__ W3,
    const float* __restrict__ W4, const float* __restrict__ W5,
    __bf16* __restrict__ out) {
  const int gidx = blockIdx.x * 256 + threadIdx.x;  // 0..12287
  const int wi = gidx >> 11;
  const int f = gidx & 2047;
  const float* W = wi == 0 ? W0 : wi == 1 ? W1 : wi == 2 ? W2
                 : wi == 3 ? W3 : wi == 4 ? W4 : W5;
  const int c = f >> 8, kk = (f >> 6) & 3, lane = f & 63;
  const int lr = lane & 15, lg = lane >> 4;
  const float* p = W + (c * 16 + lr) * FD + kk * 32 + lg * 8;
  *(bf16x8*)(out + (long)gidx * 8) = cvt8(*(const float4*)p, *(const float4*)(p + 4));
}

// A-row fragments from the swizzled row-major LDS tile; rl = local row 0..63.
// AM: 0 = f32 tile, 1 = bf16, 3 = bf16 + fused BN+relu
template <int AM>
__device__ __forceinline__ void lds_arow(const char* l, int rl, int lg,
                                         const float* __restrict__ scsh,
                                         bf16x8 (&af)[4]) {
#pragma unroll
  for (int kk = 0; kk < 4; ++kk) {
    if constexpr (AM == 0) {
      const int s0 = kk * 8 + lg * 2;
      const float4 x = *(const float4*)(l + rl * 512 + ((s0 + 0) ^ (rl & 7)) * 16);
      const float4 y = *(const float4*)(l + rl * 512 + ((s0 + 1) ^ (rl & 7)) * 16);
      af[kk] = cvt8(x, y);
    } else {
      const int s = kk * 4 + lg;
      const bf16x8 r = *(const bf16x8*)(l + rl * 256 + (s ^ (rl & 7)) * 16);
      if constexpr (AM == 3) {
        const int k = lg * 8 + kk * 32;
        const float4 scx = *(const float4*)(scsh + k);
        const float4 scy = *(const float4*)(scsh + k + 4);
        const float4 shx = *(const float4*)(scsh + 128 + k);
        const float4 shy = *(const float4*)(scsh + 128 + k + 4);
        bf16x8 o;
        o[0] = (__bf16)fmaxf((float)r[0] * scx.x + shx.x, 0.f);
        o[1] = (__bf16)fmaxf((float)r[1] * scx.y + shx.y, 0.f);
        o[2] = (__bf16)fmaxf((float)r[2] * scx.z + shx.z, 0.f);
        o[3] = (__bf16)fmaxf((float)r[3] * scx.w + shx.w, 0.f);
        o[4] = (__bf16)fmaxf((float)r[4] * scy.x + shy.x, 0.f);
        o[5] = (__bf16)fmaxf((float)r[5] * scy.y + shy.y, 0.f);
        o[6] = (__bf16)fmaxf((float)r[6] * scy.z + shy.z, 0.f);
        o[7] = (__bf16)fmaxf((float)r[7] * scy.w + shy.w, 0.f);
        af[kk] = o;
      } else {
        af[kk] = r;
      }
    }
  }
}

// out[g][M x 128] = f(A0[g]) @ W0^T (+ f(A1[g]) @ W1^T) + bias, opt relu.
// M-loop, QUAD-buffered swizzled A tiles: each phase stages tiles t+2S,t+3S,
// computes tiles t and t+S, then ONE __syncthreads -> per-tile barrier+drain
// cost halves vs r18's dbuf. Buffers staged in phase k+1 were last READ in
// phase k (protected by the phase-k barrier). W register-resident.
// Wave wid = (rw=wid&1, cw=wid>>1): rows rw*32..+32, cols cw*32..+32.
// Swapped-operand MFMA; bf16 outputs packed to 16B/lane stores via lg-pair
// __shfl_xor(.,16) (full 64B dirty lines, no write amplification).
template <int A0M, int A1M, bool TWOA, bool RELU, bool OUTBF16, bool STATS, bool WRITEB>
__global__ __launch_bounds__(512, 2) void gemm_k(
    const void* __restrict__ A0, long a0s, const void* __restrict__ A1, long a1s,
    const __bf16* __restrict__ W0p, const __bf16* __restrict__ W1p,
    const float* __restrict__ bias, const float* __restrict__ scsh0,
    void* __restrict__ outp, long os, float* __restrict__ pblk,
    __bf16* __restrict__ bcopy, int M) {
  constexpr int ASZ = (A0M == 0) ? 32768 : 16384;
  constexpr int A1SZ = TWOA ? 16384 : 0;
  constexpr int BSZ = ASZ + A1SZ;
  constexpr int LSZ = 4 * BSZ + (STATS ? 2048 : 0);
  __shared__ __align__(16) char lds[LSZ];
  float* s_red = (float*)(lds + 4 * BSZ);

  const int g = blockIdx.y;
  const int tid = threadIdx.x;
  const int wid = tid >> 6;
  const int lane = tid & 63;
  const int rw = wid & 1;
  const int cw = wid >> 1;  // 0..3
  const int lr = lane & 15;
  const int lg = lane >> 4;
  const int S = gridDim.x;

  const void* A0g = (const char*)A0 + (long)g * a0s;
  const void* A1g = (const char*)A1 + (TWOA ? (long)g * a1s : 0);
  void* outg = (char*)outp + (long)g * os;
  const float* scshg = (A0M == 3 || A1M == 3) ? scsh0 + (long)g * 256 : nullptr;

  // register-resident W fragments for this wave's 32 cols (ci = 0,1)
  bf16x8 bw0[2][4], bw1[2][4];
#pragma unroll
  for (int ci = 0; ci < 2; ++ci)
#pragma unroll
    for (int kk = 0; kk < 4; ++kk) {
      const long f = ((long)((cw * 2 + ci) * 4 + kk) * 64 + lane) * 8;
      bw0[ci][kk] = *(const bf16x8*)(W0p + f);
      if constexpr (TWOA) bw1[ci][kk] = *(const bf16x8*)(W1p + f);
    }

  float ps[2][4], pss[2][4];
  if constexpr (STATS) {
#pragma unroll
    for (int ci = 0; ci < 2; ++ci)
#pragma unroll
      for (int j = 0; j < 4; ++j) { ps[ci][j] = 0.f; pss[ci][j] = 0.f; }
  }

  auto stageA = [&](long t, char* buf) {
    if constexpr (A0M == 0) stage_a32((const float*)A0g, t * 64, M, buf, wid, lane);
    else stage_abf((const __bf16*)A0g, t * 64, M, buf, wid, lane);
    if constexpr (TWOA) stage_abf((const __bf16*)A1g, t * 64, M, buf + ASZ, wid, lane);
  };

  auto doTile = [&](long t, char* cur) {
    bf16x8 a0f[2][4];
#pragma unroll
    for (int tt = 0; tt < 2; ++tt)
      lds_arow<A0M>(cur, rw * 32 + tt * 16 + lr, lg, scshg, a0f[tt]);
    bf16x8 a1f[2][4];
    if constexpr (TWOA) {
#pragma unroll
      for (int tt = 0; tt < 2; ++tt)
        lds_arow<A1M>(cur + ASZ, rw * 32 + tt * 16 + lr, lg, scshg, a1f[tt]);
    }

    if constexpr (WRITEB) {
      if (cw == 0) {  // wids 0,1 cover all 64 tile rows
#pragma unroll
        for (int tt = 0; tt < 2; ++tt) {
          const long row = t * 64 + rw * 32 + tt * 16 + lr;
          if (row < M)
#pragma unroll
            for (int kk = 0; kk < 4; ++kk)
              *(bf16x8*)(bcopy + row * FD + lg * 8 + kk * 32) = a0f[tt][kk];
        }
      }
    }

    f32x4 acc[2][2];
#pragma unroll
    for (int tt = 0; tt < 2; ++tt)
#pragma unroll
      for (int ci = 0; ci < 2; ++ci) acc[tt][ci] = (f32x4){0.f, 0.f, 0.f, 0.f};

#pragma unroll
    for (int ci = 0; ci < 2; ++ci)
#pragma unroll
      for (int tt = 0; tt < 2; ++tt)
#pragma unroll
        for (int kk = 0; kk < 4; ++kk)
          acc[tt][ci] = __builtin_amdgcn_mfma_f32_16x16x32_bf16(bw0[ci][kk], a0f[tt][kk], acc[tt][ci], 0, 0, 0);
    if constexpr (TWOA) {
#pragma unroll
      for (int ci = 0; ci < 2; ++ci)
#pragma unroll
        for (int tt = 0; tt < 2; ++tt)
#pragma unroll
          for (int kk = 0; kk < 4; ++kk)
            acc[tt][ci] = __builtin_amdgcn_mfma_f32_16x16x32_bf16(bw1[ci][kk], a1f[tt][kk], acc[tt][ci], 0, 0, 0);
    }

#pragma unroll
    for (int tt = 0; tt < 2; ++tt) {
      const long row = t * 64 + rw * 32 + tt * 16 + lr;
      const bool ok = row < M;
      f32x4 vv[2];
#pragma unroll
      for (int ci = 0; ci < 2; ++ci) {
        const int cb = cw * 32 + ci * 16 + lg * 4;
        f32x4 v = acc[tt][ci];
        if (bias) {
          const float4 bv = *(const float4*)(bias + cb);
          v[0] += bv.x; v[1] += bv.y; v[2] += bv.z; v[3] += bv.w;
        }
        if constexpr (STATS) {
          if (ok) {
#pragma unroll
            for (int j = 0; j < 4; ++j) { ps[ci][j] += v[j]; pss[ci][j] += v[j] * v[j]; }
          }
        }
        if constexpr (RELU) {
#pragma unroll
          for (int j = 0; j < 4; ++j) v[j] = fmaxf(v[j], 0.f);
        }
        vv[ci] = v;
      }
      if constexpr (OUTBF16) {
        // pack to 16B/lane stores: exchange with lg^1 partner (same row).
        bf16x4 o0, o1;
#pragma unroll
        for (int j = 0; j < 4; ++j) { o0[j] = (__bf16)vv[0][j]; o1[j] = (__bf16)vv[1][j]; }
        const int2 i0 = __builtin_bit_cast(int2, o0);
        const int2 i1 = __builtin_bit_cast(int2, o1);
        int2 p0, p1;
        p0.x = __shfl_xor(i0.x, 16); p0.y = __shfl_xor(i0.y, 16);
        p1.x = __shfl_xor(i1.x, 16); p1.y = __shfl_xor(i1.y, 16);
        int4 chunk;
        int cbase;
        if ((lg & 1) == 0) {
          chunk = (int4){i0.x, i0.y, p0.x, p0.y};
          cbase = cw * 32 + lg * 4;
        } else {
          chunk = (int4){p1.x, p1.y, i1.x, i1.y};
          cbase = cw * 32 + 16 + (lg - 1) * 4;
        }
        if (ok) *(int4*)((__bf16*)outg + row * FD + cbase) = chunk;
      } else {
        if (ok) {
#pragma unroll
          for (int ci = 0; ci < 2; ++ci) {
            const int cb = cw * 32 + ci * 16 + lg * 4;
            *(f32x4*)((float*)outg + row * FD + cb) = vv[ci];
          }
        }
      }
    }
  };

  char* B0 = lds;
  char* B1 = lds + BSZ;
  char* B2 = lds + 2 * BSZ;
  char* B3 = lds + 3 * BSZ;

  auto phase = [&](long t, char* c0, char* c1, char* n0, char* n1) {
    const long tp2 = t + 2 * (long)S, tp3 = t + 3 * (long)S;
    if (tp2 < NT64) stageA(tp2, n0);  // prefetch issued FIRST
    if (tp3 < NT64) stageA(tp3, n1);
    doTile(t, c0);
    if (t + S < NT64) doTile(t + S, c1);
    __syncthreads();  // stages landed; c0/c1 safe to overwrite next phase
  };

  // prologue: first two tiles
  long t = blockIdx.x;
  stageA(t, B0);
  if (t + S < NT64) stageA(t + S, B1);
  __syncthreads();

  for (;;) {
    phase(t, B0, B1, B2, B3);
    t += 2 * (long)S;
    if (t >= NT64) break;
    phase(t, B2, B3, B0, B1);
    t += 2 * (long)S;
    if (t >= NT64) break;
  }

  if constexpr (STATS) {
#pragma unroll
    for (int ci = 0; ci < 2; ++ci)
#pragma unroll
      for (int j = 0; j < 4; ++j) {
        float s = ps[ci][j], q = pss[ci][j];
        s += __shfl_xor(s, 1); s += __shfl_xor(s, 2);
        s += __shfl_xor(s, 4); s += __shfl_xor(s, 8);
        q += __shfl_xor(q, 1); q += __shfl_xor(q, 2);
        q += __shfl_xor(q, 4); q += __shfl_xor(q, 8);
        if (lr == 0) {
          s_red[(0 * 8 + wid) * 32 + ci * 16 + lg * 4 + j] = s;
          s_red[(1 * 8 + wid) * 32 + ci * 16 + lg * 4 + j] = q;
        }
      }
    __syncthreads();
    if (tid < 256) {
      const int which = tid >> 7, col = tid & 127;
      const int cwi = col >> 5, cl = col & 31;
      const float a = s_red[(which * 8 + cwi * 2 + 0) * 32 + cl] +
                      s_red[(which * 8 + cwi * 2 + 1) * 32 + cl];
      pblk[((long)g * gridDim.x + blockIdx.x) * 256 + tid] = a;
    }
  }
}

// ---- BN finalize: sum per-block partials -> scale/shift (batched over g) ----
__global__ __launch_bounds__(256) void bn_final2_k(const float* __restrict__ pblk,
                                                   const float* __restrict__ gamma,
                                                   const float* __restrict__ beta,
                                                   float* __restrict__ scsh3) {
  __shared__ float s_ss[128];
  const int g = blockIdx.y;
  const int tid = threadIdx.x;
  const float* p = pblk + (long)g * GX_TWOA * 256;
  float s = 0.f;
  for (int r = 0; r < GX_TWOA; ++r) s += p[r * 256 + tid];
  if (tid >= 128) s_ss[tid - 128] = s;
  __syncthreads();
  if (tid < 128) {
    const float mu = s / (float)NNODES;
    const float var = s_ss[tid] / (float)NNODES - mu * mu;
    const float sc = rsqrtf(var + 1e-5f) * gamma[tid];
    scsh3[g * 256 + tid] = sc;
    scsh3[g * 256 + 128 + tid] = beta[tid] - mu * sc;
  }
}

// ---- batched (3-graph) counting-sort, rank-trick (atomics only in hist) ----

__global__ __launch_bounds__(256) void hist_rank3_k(const int* __restrict__ edges,
                                                    unsigned* __restrict__ deg3,
                                                    unsigned short* __restrict__ rank3) {
  const int g = blockIdx.y;
  const int e = blockIdx.x * 256 + threadIdx.x;
  if (e < NEDGES) {
    const int d = edges[(long)g * 2 * NEDGES + NEDGES + e];
    const unsigned r = atomicAdd(&deg3[(long)g * NNODES + d], 1u);
    rank3[(long)g * NEDGES + e] = (unsigned short)r;
  }
}

__global__ __launch_bounds__(256) void blocksum3_k(const unsigned* __restrict__ deg3,
                                                   unsigned* __restrict__ bsum3) {
  __shared__ unsigned s[256];
  const int g = blockIdx.y;
  const int i = blockIdx.x * 256 + threadIdx.x;
  s[threadIdx.x] = (i < NNODES) ? deg3[(long)g * NNODES + i] : 0u;
  __syncthreads();
#pragma unroll
  for (int o = 128; o > 0; o >>= 1) {
    if (threadIdx.x < o) s[threadIdx.x] += s[threadIdx.x + o];
    __syncthreads();
  }
  if (threadIdx.x == 0) bsum3[g * NB + blockIdx.x] = s[0];
}

__global__ __launch_bounds__(512) void scanb3_k(const unsigned* __restrict__ bsum3,
                                                unsigned* __restrict__ boffs3,
                                                unsigned* __restrict__ offs3) {
  __shared__ unsigned s[512];
  const int g = blockIdx.y;
  const unsigned v = (threadIdx.x < NB) ? bsum3[g * NB + threadIdx.x] : 0u;
  s[threadIdx.x] = v;
  __syncthreads();
#pragma unroll
  for (int o = 1; o < 512; o <<= 1) {
    unsigned t = (threadIdx.x >= o) ? s[threadIdx.x - o] : 0u;
    __syncthreads();
    s[threadIdx.x] += t;
    __syncthreads();
  }
  if (threadIdx.x < NB) boffs3[g * NB + threadIdx.x] = s[threadIdx.x] - v;
  if (threadIdx.x == 0) offs3[(long)g * OFFS_U32 + NNODES] = NEDGES;
}

__global__ __launch_bounds__(256) void offsets3_k(const unsigned* __restrict__ deg3,
                                                  const unsigned* __restrict__ boffs3,
                                                  unsigned* __restrict__ offs3) {
  __shared__ unsigned s[256];
  const int g = blockIdx.y;
  const int i = blockIdx.x * 256 + threadIdx.x;
  const unsigned v = (i < NNODES) ? deg3[(long)g * NNODES + i] : 0u;
  s[threadIdx.x] = v;
  __syncthreads();
#pragma unroll
  for (int o = 1; o < 256; o <<= 1) {
    unsigned t = (threadIdx.x >= o) ? s[threadIdx.x - o] : 0u;
    __syncthreads();
    s[threadIdx.x] += t;
    __syncthreads();
  }
  const unsigned excl = s[threadIdx.x] - v + boffs3[g * NB + blockIdx.x];
  if (i < NNODES) offs3[(long)g * OFFS_U32 + i] = excl;
}

__global__ __launch_bounds__(256) void scat3_k(const int* __restrict__ edges,
                                               const unsigned* __restrict__ offs3,
                                               const unsigned short* __restrict__ rank3,
                                               int* __restrict__ ssrc3) {
  const int g = blockIdx.y;
  const int e = blockIdx.x * 256 + threadIdx.x;
  if (e < NEDGES) {
    const int s = edges[(long)g * 2 * NEDGES + e];
    const int d = edges[(long)g * 2 * NEDGES + NEDGES + e];
    const unsigned p = offs3[(long)g * OFFS_U32 + d] + rank3[(long)g * NEDGES + e];
    ssrc3[(long)g * NEDGES + p] = s;
  }
}

// 16 lanes per node; max over in-edges (bf16 >= 0 -> u16 bit-compare exact).
__global__ __launch_bounds__(256) void agg_k(const unsigned short* __restrict__ m,
                                             long ms, const int* __restrict__ ssrc3,
                                             const unsigned* __restrict__ offs3,
                                             unsigned short* __restrict__ agg3) {
  const int g = blockIdx.y;
  const unsigned short* mg = m + (long)g * ms;
  const int* ssrc = ssrc3 + (long)g * NEDGES;
  const unsigned* offs = offs3 + (long)g * OFFS_U32;
  unsigned short* agg = agg3 + (long)g * NNODES * FD;

  const int gid = blockIdx.x * 256 + threadIdx.x;
  const int node = gid >> 4;
  if (node >= NNODES) return;
  const int fl = (gid & 15) * 8;
  const unsigned beg = offs[node], end = offs[node + 1];
  u16x8 acc = {0, 0, 0, 0, 0, 0, 0, 0};
  unsigned i = beg;
  for (; i + 2 <= end; i += 2) {
    const int s0 = ssrc[i];
    const int s1 = ssrc[i + 1];
    const u16x8 v0 = *(const u16x8*)(mg + (long)s0 * FD + fl);
    const u16x8 v1 = *(const u16x8*)(mg + (long)s1 * FD + fl);
#pragma unroll
    for (int j = 0; j < 8; ++j) {
      const unsigned short mx = v0[j] > v1[j] ? v0[j] : v1[j];
      acc[j] = mx > acc[j] ? mx : acc[j];
    }
  }
  if (i < end) {
    const u16x8 v = *(const u16x8*)(mg + (long)ssrc[i] * FD + fl);
#pragma unroll
    for (int j = 0; j < 8; ++j) acc[j] = v[j] > acc[j] ? v[j] : acc[j];
  }
  *(u16x8*)(agg + (long)node * FD + fl) = acc;
}

__global__ __launch_bounds__(256) void zero_k(float4* __restrict__ p, long n4) {
  const long i = (long)blockIdx.x * 256 + threadIdx.x;
  if (i < n4) p[i] = (float4){0.f, 0.f, 0.f, 0.f};
}

extern "C" void kernel_launch(void* const* d_in, const int* in_sizes, int n_in,
                              void* d_out, int out_size, void* d_ws, size_t ws_size,
                              hipStream_t stream) {
  const float* feat = (const float*)d_in[0];
  const int* edges = (const int*)d_in[1];
  const float* Wp1 = (const float*)d_in[2];
  const float* bp1 = (const float*)d_in[3];
  const float* Ws1 = (const float*)d_in[4];
  const float* Wn1 = (const float*)d_in[5];
  const float* b1 = (const float*)d_in[6];
  const float* gamma = (const float*)d_in[7];
  const float* beta = (const float*)d_in[8];
  const float* Wp2 = (const float*)d_in[9];
  const float* bp2 = (const float*)d_in[10];
  const float* Ws2 = (const float*)d_in[11];
  const float* Wn2 = (const float*)d_in[12];
  const float* b2 = (const float*)d_in[13];

  const long SZ_BF = 25600000;   // bf16 [N][128] bytes
  const long SZ_F32 = 51200000;  // f32  [N][128] bytes

  // workspace layout (bytes, 128B-aligned)
  char* w = (char*)d_ws;
  __bf16* m1 = (__bf16*)w;                          // 25.6 MB
  __bf16* featb = (__bf16*)(w + 25600000);          // 25.6 MB
  __bf16* h1b3 = (__bf16*)(w + 51200000);           // 76.8 MB (3x pre-BN h1)
  __bf16* aggb3 = (__bf16*)(w + 128000000);         // 76.8 MB
  __bf16* m2_3 = (__bf16*)(w + 204800000);          // 76.8 MB
  // pblk3 aliases the m2_3 region: dead before m2 is written
  float* pblk3 = (float*)(w + 204800000);           // 261 KB (3 x 85 x 256)
  __bf16* wpk = (__bf16*)(w + 281600000);           // 192 KB packed weights
  float* scsh3 = (float*)(w + 281796608);           // 3 KB
  unsigned* deg3 = (unsigned*)(w + 281799680);      // 1.2 MB
  unsigned* offs3 = (unsigned*)(w + 282999680);     // 1.2 MB
  unsigned* bsum3 = (unsigned*)(w + 284200064);     // 4.7 KB
  unsigned* boffs3 = (unsigned*)(w + 284204928);    // 4.7 KB
  unsigned short* rank3 = (unsigned short*)(w + 284209792);  // 3.84 MB
  int* ssrc3 = (int*)(w + 288049792);               // 7.68 MB

  __bf16* Wp1p = wpk;
  __bf16* Ws1p = wpk + 16384;
  __bf16* Wn1p = wpk + 2 * 16384;
  __bf16* Wp2p = wpk + 3 * 16384;
  __bf16* Ws2p = wpk + 4 * 16384;
  __bf16* Wn2p = wpk + 5 * 16384;

  const dim3 blk(256);
  const dim3 blk512(512);
  const int edgeGrid = (NEDGES + 255) / 256;             // 2500
  const int aggGrid = (NNODES * 16 + 255) / 256;         // 6250
  const int degZeroGrid = (3 * NNODES / 4 + 255) / 256;  // 293

  // pack all weights in one dispatch
  packw6_k<<<48, blk, 0, stream>>>(Wp1, Ws1, Wn1, Wp2, Ws2, Wn2, wpk);

  // batched edge bucketing (counting sort by dst) for all 3 graphs
  zero_k<<<degZeroGrid, blk, 0, stream>>>((float4*)deg3, 3L * NNODES / 4);
  hist_rank3_k<<<dim3(edgeGrid, 3), blk, 0, stream>>>(edges, deg3, rank3);
  blocksum3_k<<<dim3(NB, 3), blk, 0, stream>>>(deg3, bsum3);
  scanb3_k<<<dim3(1, 3), dim3(512), 0, stream>>>(bsum3, boffs3, offs3);
  offsets3_k<<<dim3(NB, 3), blk, 0, stream>>>(deg3, boffs3, offs3);
  scat3_k<<<dim3(edgeGrid, 3), blk, 0, stream>>>(edges, offs3, rank3, ssrc3);

  // head: m1 = relu(feat@Wp1^T + bp1) (bf16), plus featb = bf16(feat)
  gemm_k<0, 0, false, true, true, false, true><<<dim3(GX_HEAD, 1), blk512, 0, stream>>>(
      feat, 0, nullptr, 0, Wp1p, nullptr, bp1, nullptr, m1, 0, nullptr, featb, NNODES);

  // layer 1 (batched): agg1[g] = segmax_g(m1);
  // h1[g] = agg1[g]@Wn1^T + featb@Ws1^T + b1 (bf16) + fused BN stats
  agg_k<<<dim3(aggGrid, 3), blk, 0, stream>>>((const unsigned short*)m1, 0L,
                                              ssrc3, offs3, (unsigned short*)aggb3);
  gemm_k<1, 1, true, false, true, true, false><<<dim3(GX_TWOA, 3), blk512, 0, stream>>>(
      aggb3, SZ_BF, featb, 0, Wn1p, Ws1p, b1, nullptr, h1b3, SZ_BF, pblk3, nullptr, NNODES);
  bn_final2_k<<<dim3(1, 3), blk, 0, stream>>>(pblk3, gamma, beta, scsh3);

  // layer 2 (batched): m2[g] = relu(bnrelu(h1[g])@Wp2^T + bp2)
  gemm_k<3, 0, false, true, true, false, false><<<dim3(GX_ONEW, 3), blk512, 0, stream>>>(
      h1b3, SZ_BF, nullptr, 0, Wp2p, nullptr, bp2, scsh3, m2_3, SZ_BF, nullptr, nullptr, NNODES);
  agg_k<<<dim3(aggGrid, 3), blk, 0, stream>>>((const unsigned short*)m2_3,
                                              (long)NNODES * FD, ssrc3, offs3,
                                              (unsigned short*)aggb3);
  // out[g] = bnrelu(h1[g])@Ws2^T + agg2[g]@Wn2^T + b2 -> d_out (f32)
  gemm_k<3, 1, true, false, false, false, false><<<dim3(GX_TWOA, 3), blk512, 0, stream>>>(
      h1b3, SZ_BF, aggb3, SZ_BF, Ws2p, Wn2p, b2, scsh3, d_out, SZ_F32, nullptr, nullptr, NNODES);
}

// Round 20
// 485.180 us; speedup vs baseline: 1.7033x; 1.7033x over previous
//
#include <hip/hip_runtime.h>
#include <hip/hip_bf16.h>

#define NNODES 100000
#define FD 128
#define NEDGES 640000
#define NB 391            // ceil(NNODES/256)
#define NT64 1563         // ceil(NNODES/64): 64-row tiles
#define GX_TWOA 170       // dual-A gemms: 510 blocks, 2/CU (66KB LDS)
#define GX_ONEW 340       // single-A bf16 gemm: 1020 blocks (32KB LDS)
#define GX_HEAD 512       // head f32 gemm: 512 blocks, 2/CU (64KB LDS)
#define OFFS_U32 100032   // padded NNODES+1

typedef __bf16 bf16x8 __attribute__((ext_vector_type(8)));
typedef __bf16 bf16x4 __attribute__((ext_vector_type(4)));
typedef float f32x4 __attribute__((ext_vector_type(4)));
typedef unsigned short u16x8 __attribute__((ext_vector_type(8)));

__device__ __forceinline__ bf16x8 cvt8(float4 a, float4 b) {
  bf16x8 r;
  r[0] = (__bf16)a.x; r[1] = (__bf16)a.y; r[2] = (__bf16)a.z; r[3] = (__bf16)a.w;
  r[4] = (__bf16)b.x; r[5] = (__bf16)b.y; r[6] = (__bf16)b.z; r[7] = (__bf16)b.w;
  return r;
}

// async global->LDS, 16B/lane; LDS dest = wave-uniform base + lane*16
__device__ __forceinline__ void gl16(const void* g, void* l) {
  __builtin_amdgcn_global_load_lds(
      (const __attribute__((address_space(1))) unsigned int*)g,
      (__attribute__((address_space(3))) unsigned int*)l, 16, 0, 0);
}

// stage 64-row bf16 tile ROW-MAJOR with XOR-swizzled 16B slots:
// LDS[rl][p] = A[row0+rl][p ^ (rl&7)]  (p = 16B unit 0..15).
// Each gl16 reads 1KB CONTIGUOUS (4 rows x 256B; permutation stays inside
// each row) -> fully-used cache lines. Wave w stages rows 8w..8w+7.
__device__ __forceinline__ void stage_abf(const __bf16* A, long row0, int M,
                                          char* l, int wid, int lane) {
#pragma unroll
  for (int i = 0; i < 2; ++i) {
    const int r0 = wid * 8 + i * 4;       // wave-uniform: 4 rows / instruction
    const int rl = r0 + (lane >> 4);
    long row = row0 + rl;
    if (row > M - 1) row = M - 1;         // clamp; stores guarded in epilogue
    const int slot = (lane & 15) ^ (rl & 7);
    gl16((const char*)(A + row * FD) + slot * 16, l + r0 * 256);
  }
}

// stage 64-row f32 tile row-major (512B rows, 32 slots), same swizzle
__device__ __forceinline__ void stage_a32(const float* A, long row0, int M,
                                          char* l, int wid, int lane) {
#pragma unroll
  for (int i = 0; i < 4; ++i) {
    const int r0 = wid * 8 + i * 2;       // 2 rows / instruction
    const int rl = r0 + (lane >> 5);
    long row = row0 + rl;
    if (row > M - 1) row = M - 1;
    const int slot = (lane & 31) ^ (rl & 7);
    gl16((const char*)(A + row * FD) + slot * 16, l + r0 * 512);
  }
}

// ---- pack all 6 weight matrices f32[128][128] -> bf16 MFMA fragments ----
// frag f = (c*4+kk)*64 + lane; elem j = W[(c*16+(lane&15))][kk*32+(lane>>4)*8+j]
__global__ __launch_bounds__(256) void packw6_k(
    const float* __restrict__ W0, const float* __restrict__ W1,
    const float* __restrict__ W2, const float* __restrict__ W3,
    const float* __restrict__ W4, const float* __restrict__ W5,
    __bf16* __restrict__ out) {
  const int gidx = blockIdx.x * 256 + threadIdx.x;  // 0..12287
  const int wi = gidx >> 11;
  const int f = gidx & 2047;
  const float* W = wi == 0 ? W0 : wi == 1 ? W1 : wi == 2 ? W2
                 : wi == 3 ? W3 : wi == 4 ? W4 : W5;
  const int c = f >> 8, kk = (f >> 6) & 3, lane = f & 63;
  const int lr = lane & 15, lg = lane >> 4;
  const float* p = W + (c * 16 + lr) * FD + kk * 32 + lg * 8;
  *(bf16x8*)(out + (long)gidx * 8) = cvt8(*(const float4*)p, *(const float4*)(p + 4));
}

// A-row fragments from the swizzled row-major LDS tile; rl = local row 0..63.
// AM: 0 = f32 tile, 1 = bf16, 3 = bf16 + fused BN+relu
template <int AM>
__device__ __forceinline__ void lds_arow(const char* l, int rl, int lg,
                                         const float* __restrict__ scsh,
                                         bf16x8 (&af)[4]) {
#pragma unroll
  for (int kk = 0; kk < 4; ++kk) {
    if constexpr (AM == 0) {
      const int s0 = kk * 8 + lg * 2;
      const float4 x = *(const float4*)(l + rl * 512 + ((s0 + 0) ^ (rl & 7)) * 16);
      const float4 y = *(const float4*)(l + rl * 512 + ((s0 + 1) ^ (rl & 7)) * 16);
      af[kk] = cvt8(x, y);
    } else {
      const int s = kk * 4 + lg;
      const bf16x8 r = *(const bf16x8*)(l + rl * 256 + (s ^ (rl & 7)) * 16);
      if constexpr (AM == 3) {
        const int k = lg * 8 + kk * 32;
        const float4 scx = *(const float4*)(scsh + k);
        const float4 scy = *(const float4*)(scsh + k + 4);
        const float4 shx = *(const float4*)(scsh + 128 + k);
        const float4 shy = *(const float4*)(scsh + 128 + k + 4);
        bf16x8 o;
        o[0] = (__bf16)fmaxf((float)r[0] * scx.x + shx.x, 0.f);
        o[1] = (__bf16)fmaxf((float)r[1] * scx.y + shx.y, 0.f);
        o[2] = (__bf16)fmaxf((float)r[2] * scx.z + shx.z, 0.f);
        o[3] = (__bf16)fmaxf((float)r[3] * scx.w + shx.w, 0.f);
        o[4] = (__bf16)fmaxf((float)r[4] * scy.x + shy.x, 0.f);
        o[5] = (__bf16)fmaxf((float)r[5] * scy.y + shy.y, 0.f);
        o[6] = (__bf16)fmaxf((float)r[6] * scy.z + shy.z, 0.f);
        o[7] = (__bf16)fmaxf((float)r[7] * scy.w + shy.w, 0.f);
        af[kk] = o;
      } else {
        af[kk] = r;
      }
    }
  }
}

// out[g][M x 128] = f(A0[g]) @ W0^T (+ f(A1[g]) @ W1^T) + bias, opt relu.
// M-loop, double-buffered swizzled A tiles (coalesced stage), W register-
// resident. Per iter: stage A(t+1) -> ds_read A(t) -> MFMA -> stores ->
// __syncthreads. 2 blocks/CU overlap each other's barrier drains.
// Wave wid = (rw=wid&1, cw=wid>>1): rows rw*32..+32, cols cw*32..+32.
// Swapped-operand MFMA: lane holds D[row=t*64+rw*32+tt*16+lr]
// [col=cw*32+ci*16+lg*4+j]. bf16 outputs are PACKED to 16B/lane stores via
// lg-pair __shfl_xor(.,16) so every store instruction dirties full 64B lines.
// NTOUT: f32 output stored nontemporal (write-once d_out; full 64B sectors,
// no RMW risk) to avoid evicting the L2/L3-resident A operands.
template <int A0M, int A1M, bool TWOA, bool RELU, bool OUTBF16, bool STATS,
          bool WRITEB, bool NTOUT>
__global__ __launch_bounds__(512, 2) void gemm_k(
    const void* __restrict__ A0, long a0s, const void* __restrict__ A1, long a1s,
    const __bf16* __restrict__ W0p, const __bf16* __restrict__ W1p,
    const float* __restrict__ bias, const float* __restrict__ scsh0,
    void* __restrict__ outp, long os, float* __restrict__ pblk,
    __bf16* __restrict__ bcopy, int M) {
  constexpr int ASZ = (A0M == 0) ? 32768 : 16384;
  constexpr int A1SZ = TWOA ? 16384 : 0;
  constexpr int BSZ = ASZ + A1SZ;
  constexpr int LSZ = 2 * BSZ + (STATS ? 2048 : 0);
  __shared__ __align__(16) char lds[LSZ];
  float* s_red = (float*)(lds + 2 * BSZ);

  const int g = blockIdx.y;
  const int tid = threadIdx.x;
  const int wid = tid >> 6;
  const int lane = tid & 63;
  const int rw = wid & 1;
  const int cw = wid >> 1;  // 0..3
  const int lr = lane & 15;
  const int lg = lane >> 4;
  const int S = gridDim.x;

  const void* A0g = (const char*)A0 + (long)g * a0s;
  const void* A1g = (const char*)A1 + (TWOA ? (long)g * a1s : 0);
  void* outg = (char*)outp + (long)g * os;
  const float* scshg = (A0M == 3 || A1M == 3) ? scsh0 + (long)g * 256 : nullptr;

  // register-resident W fragments for this wave's 32 cols (ci = 0,1)
  bf16x8 bw0[2][4], bw1[2][4];
#pragma unroll
  for (int ci = 0; ci < 2; ++ci)
#pragma unroll
    for (int kk = 0; kk < 4; ++kk) {
      const long f = ((long)((cw * 2 + ci) * 4 + kk) * 64 + lane) * 8;
      bw0[ci][kk] = *(const bf16x8*)(W0p + f);
      if constexpr (TWOA) bw1[ci][kk] = *(const bf16x8*)(W1p + f);
    }

  float ps[2][4], pss[2][4];
  if constexpr (STATS) {
#pragma unroll
    for (int ci = 0; ci < 2; ++ci)
#pragma unroll
      for (int j = 0; j < 4; ++j) { ps[ci][j] = 0.f; pss[ci][j] = 0.f; }
  }

  auto stageA = [&](long t, char* buf) {
    if constexpr (A0M == 0) stage_a32((const float*)A0g, t * 64, M, buf, wid, lane);
    else stage_abf((const __bf16*)A0g, t * 64, M, buf, wid, lane);
    if constexpr (TWOA) stage_abf((const __bf16*)A1g, t * 64, M, buf + ASZ, wid, lane);
  };

  auto body = [&](long t, long tn, char* cur, char* nxt) {
    if (tn < NT64) stageA(tn, nxt);  // prefetch issued FIRST

    bf16x8 a0f[2][4];
#pragma unroll
    for (int tt = 0; tt < 2; ++tt)
      lds_arow<A0M>(cur, rw * 32 + tt * 16 + lr, lg, scshg, a0f[tt]);
    bf16x8 a1f[2][4];
    if constexpr (TWOA) {
#pragma unroll
      for (int tt = 0; tt < 2; ++tt)
        lds_arow<A1M>(cur + ASZ, rw * 32 + tt * 16 + lr, lg, scshg, a1f[tt]);
    }

    if constexpr (WRITEB) {
      if (cw == 0) {  // wids 0,1 cover all 64 tile rows
#pragma unroll
        for (int tt = 0; tt < 2; ++tt) {
          const long row = t * 64 + rw * 32 + tt * 16 + lr;
          if (row < M)
#pragma unroll
            for (int kk = 0; kk < 4; ++kk)
              *(bf16x8*)(bcopy + row * FD + lg * 8 + kk * 32) = a0f[tt][kk];
        }
      }
    }

    f32x4 acc[2][2];
#pragma unroll
    for (int tt = 0; tt < 2; ++tt)
#pragma unroll
      for (int ci = 0; ci < 2; ++ci) acc[tt][ci] = (f32x4){0.f, 0.f, 0.f, 0.f};

#pragma unroll
    for (int ci = 0; ci < 2; ++ci)
#pragma unroll
      for (int tt = 0; tt < 2; ++tt)
#pragma unroll
        for (int kk = 0; kk < 4; ++kk)
          acc[tt][ci] = __builtin_amdgcn_mfma_f32_16x16x32_bf16(bw0[ci][kk], a0f[tt][kk], acc[tt][ci], 0, 0, 0);
    if constexpr (TWOA) {
#pragma unroll
      for (int ci = 0; ci < 2; ++ci)
#pragma unroll
        for (int tt = 0; tt < 2; ++tt)
#pragma unroll
          for (int kk = 0; kk < 4; ++kk)
            acc[tt][ci] = __builtin_amdgcn_mfma_f32_16x16x32_bf16(bw1[ci][kk], a1f[tt][kk], acc[tt][ci], 0, 0, 0);
    }

#pragma unroll
    for (int tt = 0; tt < 2; ++tt) {
      const long row = t * 64 + rw * 32 + tt * 16 + lr;
      const bool ok = row < M;
      f32x4 vv[2];
#pragma unroll
      for (int ci = 0; ci < 2; ++ci) {
        const int cb = cw * 32 + ci * 16 + lg * 4;
        f32x4 v = acc[tt][ci];
        if (bias) {
          const float4 bv = *(const float4*)(bias + cb);
          v[0] += bv.x; v[1] += bv.y; v[2] += bv.z; v[3] += bv.w;
        }
        if constexpr (STATS) {
          if (ok) {
#pragma unroll
            for (int j = 0; j < 4; ++j) { ps[ci][j] += v[j]; pss[ci][j] += v[j] * v[j]; }
          }
        }
        if constexpr (RELU) {
#pragma unroll
          for (int j = 0; j < 4; ++j) v[j] = fmaxf(v[j], 0.f);
        }
        vv[ci] = v;
      }
      if constexpr (OUTBF16) {
        // pack to 16B/lane stores: exchange with lg^1 partner (same row).
        bf16x4 o0, o1;
#pragma unroll
        for (int j = 0; j < 4; ++j) { o0[j] = (__bf16)vv[0][j]; o1[j] = (__bf16)vv[1][j]; }
        const int2 i0 = __builtin_bit_cast(int2, o0);
        const int2 i1 = __builtin_bit_cast(int2, o1);
        int2 p0, p1;
        p0.x = __shfl_xor(i0.x, 16); p0.y = __shfl_xor(i0.y, 16);
        p1.x = __shfl_xor(i1.x, 16); p1.y = __shfl_xor(i1.y, 16);
        int4 chunk;
        int cbase;
        if ((lg & 1) == 0) {  // ci=0 halves: own cols lg*4, partner (lg+1)*4
          chunk = (int4){i0.x, i0.y, p0.x, p0.y};
          cbase = cw * 32 + lg * 4;
        } else {              // ci=1 halves: partner (lg-1)*4 first, then own
          chunk = (int4){p1.x, p1.y, i1.x, i1.y};
          cbase = cw * 32 + 16 + (lg - 1) * 4;
        }
        if (ok) *(int4*)((__bf16*)outg + row * FD + cbase) = chunk;
      } else {
        if (ok) {
#pragma unroll
          for (int ci = 0; ci < 2; ++ci) {
            const int cb = cw * 32 + ci * 16 + lg * 4;
            f32x4* p = (f32x4*)((float*)outg + row * FD + cb);
            if constexpr (NTOUT) __builtin_nontemporal_store(vv[ci], p);
            else *p = vv[ci];
          }
        }
      }
    }
    __syncthreads();  // next stage landed; buffers safe to swap
  };

  // prologue: first A tile
  long t = blockIdx.x;
  stageA(t, lds);
  __syncthreads();

  for (;;) {
    long tn = t + S;
    body(t, tn, lds, lds + BSZ);
    t = tn;
    if (t >= NT64) break;
    tn = t + S;
    body(t, tn, lds + BSZ, lds);
    t = tn;
    if (t >= NT64) break;
  }

  if constexpr (STATS) {
#pragma unroll
    for (int ci = 0; ci < 2; ++ci)
#pragma unroll
      for (int j = 0; j < 4; ++j) {
        float s = ps[ci][j], q = pss[ci][j];
        s += __shfl_xor(s, 1); s += __shfl_xor(s, 2);
        s += __shfl_xor(s, 4); s += __shfl_xor(s, 8);
        q += __shfl_xor(q, 1); q += __shfl_xor(q, 2);
        q += __shfl_xor(q, 4); q += __shfl_xor(q, 8);
        if (lr == 0) {
          s_red[(0 * 8 + wid) * 32 + ci * 16 + lg * 4 + j] = s;
          s_red[(1 * 8 + wid) * 32 + ci * 16 + lg * 4 + j] = q;
        }
      }
    __syncthreads();
    if (tid < 256) {
      const int which = tid >> 7, col = tid & 127;
      const int cwi = col >> 5, cl = col & 31;
      const float a = s_red[(which * 8 + cwi * 2 + 0) * 32 + cl] +
                      s_red[(which * 8 + cwi * 2 + 1) * 32 + cl];
      pblk[((long)g * gridDim.x + blockIdx.x) * 256 + tid] = a;
    }
  }
}

// ---- BN finalize: sum per-block partials -> scale/shift (batched over g) ----
__global__ __launch_bounds__(256) void bn_final2_k(const float* __restrict__ pblk,
                                                   const float* __restrict__ gamma,
                                                   const float* __restrict__ beta,
                                                   float* __restrict__ scsh3) {
  __shared__ float s_ss[128];
  const int g = blockIdx.y;
  const int tid = threadIdx.x;
  const float* p = pblk + (long)g * GX_TWOA * 256;
  float s = 0.f;
  for (int r = 0; r < GX_TWOA; ++r) s += p[r * 256 + tid];
  if (tid >= 128) s_ss[tid - 128] = s;
  __syncthreads();
  if (tid < 128) {
    const float mu = s / (float)NNODES;
    const float var = s_ss[tid] / (float)NNODES - mu * mu;
    const float sc = rsqrtf(var + 1e-5f) * gamma[tid];
    scsh3[g * 256 + tid] = sc;
    scsh3[g * 256 + 128 + tid] = beta[tid] - mu * sc;
  }
}

// ---- batched (3-graph) counting-sort, rank-trick (atomics only in hist) ----

__global__ __launch_bounds__(256) void hist_rank3_k(const int* __restrict__ edges,
                                                    unsigned* __restrict__ deg3,
                                                    unsigned short* __restrict__ rank3) {
  const int g = blockIdx.y;
  const int e = blockIdx.x * 256 + threadIdx.x;
  if (e < NEDGES) {
    const int d = edges[(long)g * 2 * NEDGES + NEDGES + e];
    const unsigned r = atomicAdd(&deg3[(long)g * NNODES + d], 1u);
    rank3[(long)g * NEDGES + e] = (unsigned short)r;
  }
}

__global__ __launch_bounds__(256) void blocksum3_k(const unsigned* __restrict__ deg3,
                                                   unsigned* __restrict__ bsum3) {
  __shared__ unsigned s[256];
  const int g = blockIdx.y;
  const int i = blockIdx.x * 256 + threadIdx.x;
  s[threadIdx.x] = (i < NNODES) ? deg3[(long)g * NNODES + i] : 0u;
  __syncthreads();
#pragma unroll
  for (int o = 128; o > 0; o >>= 1) {
    if (threadIdx.x < o) s[threadIdx.x] += s[threadIdx.x + o];
    __syncthreads();
  }
  if (threadIdx.x == 0) bsum3[g * NB + blockIdx.x] = s[0];
}

__global__ __launch_bounds__(512) void scanb3_k(const unsigned* __restrict__ bsum3,
                                                unsigned* __restrict__ boffs3,
                                                unsigned* __restrict__ offs3) {
  __shared__ unsigned s[512];
  const int g = blockIdx.y;
  const unsigned v = (threadIdx.x < NB) ? bsum3[g * NB + threadIdx.x] : 0u;
  s[threadIdx.x] = v;
  __syncthreads();
#pragma unroll
  for (int o = 1; o < 512; o <<= 1) {
    unsigned t = (threadIdx.x >= o) ? s[threadIdx.x - o] : 0u;
    __syncthreads();
    s[threadIdx.x] += t;
    __syncthreads();
  }
  if (threadIdx.x < NB) boffs3[g * NB + threadIdx.x] = s[threadIdx.x] - v;
  if (threadIdx.x == 0) offs3[(long)g * OFFS_U32 + NNODES] = NEDGES;
}

__global__ __launch_bounds__(256) void offsets3_k(const unsigned* __restrict__ deg3,
                                                  const unsigned* __restrict__ boffs3,
                                                  unsigned* __restrict__ offs3) {
  __shared__ unsigned s[256];
  const int g = blockIdx.y;
  const int i = blockIdx.x * 256 + threadIdx.x;
  const unsigned v = (i < NNODES) ? deg3[(long)g * NNODES + i] : 0u;
  s[threadIdx.x] = v;
  __syncthreads();
#pragma unroll
  for (int o = 1; o < 256; o <<= 1) {
    unsigned t = (threadIdx.x >= o) ? s[threadIdx.x - o] : 0u;
    __syncthreads();
    s[threadIdx.x] += t;
    __syncthreads();
  }
  const unsigned excl = s[threadIdx.x] - v + boffs3[g * NB + blockIdx.x];
  if (i < NNODES) offs3[(long)g * OFFS_U32 + i] = excl;
}

__global__ __launch_bounds__(256) void scat3_k(const int* __restrict__ edges,
                                               const unsigned* __restrict__ offs3,
                                               const unsigned short* __restrict__ rank3,
                                               int* __restrict__ ssrc3) {
  const int g = blockIdx.y;
  const int e = blockIdx.x * 256 + threadIdx.x;
  if (e < NEDGES) {
    const int s = edges[(long)g * 2 * NEDGES + e];
    const int d = edges[(long)g * 2 * NEDGES + NEDGES + e];
    const unsigned p = offs3[(long)g * OFFS_U32 + d] + rank3[(long)g * NEDGES + e];
    ssrc3[(long)g * NEDGES + p] = s;
  }
}

// 16 lanes per node; max over in-edges (bf16 >= 0 -> u16 bit-compare exact).
__global__ __launch_bounds__(256) void agg_k(const unsigned short* __restrict__ m,
                                             long ms, const int* __restrict__ ssrc3,
                                             const unsigned* __restrict__ offs3,
                                             unsigned short* __restrict__ agg3) {
  const int g = blockIdx.y;
  const unsigned short* mg = m + (long)g * ms;
  const int* ssrc = ssrc3 + (long)g * NEDGES;
  const unsigned* offs = offs3 + (long)g * OFFS_U32;
  unsigned short* agg = agg3 + (long)g * NNODES * FD;

  const int gid = blockIdx.x * 256 + threadIdx.x;
  const int node = gid >> 4;
  if (node >= NNODES) return;
  const int fl = (gid & 15) * 8;
  const unsigned beg = offs[node], end = offs[node + 1];
  u16x8 acc = {0, 0, 0, 0, 0, 0, 0, 0};
  unsigned i = beg;
  for (; i + 2 <= end; i += 2) {
    const int s0 = ssrc[i];
    const int s1 = ssrc[i + 1];
    const u16x8 v0 = *(const u16x8*)(mg + (long)s0 * FD + fl);
    const u16x8 v1 = *(const u16x8*)(mg + (long)s1 * FD + fl);
#pragma unroll
    for (int j = 0; j < 8; ++j) {
      const unsigned short mx = v0[j] > v1[j] ? v0[j] : v1[j];
      acc[j] = mx > acc[j] ? mx : acc[j];
    }
  }
  if (i < end) {
    const u16x8 v = *(const u16x8*)(mg + (long)ssrc[i] * FD + fl);
#pragma unroll
    for (int j = 0; j < 8; ++j) acc[j] = v[j] > acc[j] ? v[j] : acc[j];
  }
  *(u16x8*)(agg + (long)node * FD + fl) = acc;
}

__global__ __launch_bounds__(256) void zero_k(float4* __restrict__ p, long n4) {
  const long i = (long)blockIdx.x * 256 + threadIdx.x;
  if (i < n4) p[i] = (float4){0.f, 0.f, 0.f, 0.f};
}

extern "C" void kernel_launch(void* const* d_in, const int* in_sizes, int n_in,
                              void* d_out, int out_size, void* d_ws, size_t ws_size,
                              hipStream_t stream) {
  const float* feat = (const float*)d_in[0];
  const int* edges = (const int*)d_in[1];
  const float* Wp1 = (const float*)d_in[2];
  const float* bp1 = (const float*)d_in[3];
  const float* Ws1 = (const float*)d_in[4];
  const float* Wn1 = (const float*)d_in[5];
  const float* b1 = (const float*)d_in[6];
  const float* gamma = (const float*)d_in[7];
  const float* beta = (const float*)d_in[8];
  const float* Wp2 = (const float*)d_in[9];
  const float* bp2 = (const float*)d_in[10];
  const float* Ws2 = (const float*)d_in[11];
  const float* Wn2 = (const float*)d_in[12];
  const float* b2 = (const float*)d_in[13];

  const long SZ_BF = 25600000;   // bf16 [N][128] bytes
  const long SZ_F32 = 51200000;  // f32  [N][128] bytes

  // workspace layout (bytes, 128B-aligned)
  char* w = (char*)d_ws;
  __bf16* m1 = (__bf16*)w;                          // 25.6 MB
  __bf16* featb = (__bf16*)(w + 25600000);          // 25.6 MB
  __bf16* h1b3 = (__bf16*)(w + 51200000);           // 76.8 MB (3x pre-BN h1)
  __bf16* aggb3 = (__bf16*)(w + 128000000);         // 76.8 MB
  __bf16* m2_3 = (__bf16*)(w + 204800000);          // 76.8 MB
  // pblk3 aliases the m2_3 region: dead before m2 is written
  float* pblk3 = (float*)(w + 204800000);           // 522 KB (3 x 170 x 256)
  __bf16* wpk = (__bf16*)(w + 281600000);           // 192 KB packed weights
  float* scsh3 = (float*)(w + 281796608);           // 3 KB
  unsigned* deg3 = (unsigned*)(w + 281799680);      // 1.2 MB
  unsigned* offs3 = (unsigned*)(w + 282999680);     // 1.2 MB
  unsigned* bsum3 = (unsigned*)(w + 284200064);     // 4.7 KB
  unsigned* boffs3 = (unsigned*)(w + 284204928);    // 4.7 KB
  unsigned short* rank3 = (unsigned short*)(w + 284209792);  // 3.84 MB
  int* ssrc3 = (int*)(w + 288049792);               // 7.68 MB

  __bf16* Wp1p = wpk;
  __bf16* Ws1p = wpk + 16384;
  __bf16* Wn1p = wpk + 2 * 16384;
  __bf16* Wp2p = wpk + 3 * 16384;
  __bf16* Ws2p = wpk + 4 * 16384;
  __bf16* Wn2p = wpk + 5 * 16384;

  const dim3 blk(256);
  const dim3 blk512(512);
  const int edgeGrid = (NEDGES + 255) / 256;             // 2500
  const int aggGrid = (NNODES * 16 + 255) / 256;         // 6250
  const int degZeroGrid = (3 * NNODES / 4 + 255) / 256;  // 293

  // pack all weights in one dispatch
  packw6_k<<<48, blk, 0, stream>>>(Wp1, Ws1, Wn1, Wp2, Ws2, Wn2, wpk);

  // batched edge bucketing (counting sort by dst) for all 3 graphs
  zero_k<<<degZeroGrid, blk, 0, stream>>>((float4*)deg3, 3L * NNODES / 4);
  hist_rank3_k<<<dim3(edgeGrid, 3), blk, 0, stream>>>(edges, deg3, rank3);
  blocksum3_k<<<dim3(NB, 3), blk, 0, stream>>>(deg3, bsum3);
  scanb3_k<<<dim3(1, 3), dim3(512), 0, stream>>>(bsum3, boffs3, offs3);
  offsets3_k<<<dim3(NB, 3), blk, 0, stream>>>(deg3, boffs3, offs3);
  scat3_k<<<dim3(edgeGrid, 3), blk, 0, stream>>>(edges, offs3, rank3, ssrc3);

  // head: m1 = relu(feat@Wp1^T + bp1) (bf16), plus featb = bf16(feat)
  gemm_k<0, 0, false, true, true, false, true, false><<<dim3(GX_HEAD, 1), blk512, 0, stream>>>(
      feat, 0, nullptr, 0, Wp1p, nullptr, bp1, nullptr, m1, 0, nullptr, featb, NNODES);

  // layer 1 (batched): agg1[g] = segmax_g(m1);
  // h1[g] = agg1[g]@Wn1^T + featb@Ws1^T + b1 (bf16) + fused BN stats
  agg_k<<<dim3(aggGrid, 3), blk, 0, stream>>>((const unsigned short*)m1, 0L,
                                              ssrc3, offs3, (unsigned short*)aggb3);
  gemm_k<1, 1, true, false, true, true, false, false><<<dim3(GX_TWOA, 3), blk512, 0, stream>>>(
      aggb3, SZ_BF, featb, 0, Wn1p, Ws1p, b1, nullptr, h1b3, SZ_BF, pblk3, nullptr, NNODES);
  bn_final2_k<<<dim3(1, 3), blk, 0, stream>>>(pblk3, gamma, beta, scsh3);

  // layer 2 (batched): m2[g] = relu(bnrelu(h1[g])@Wp2^T + bp2)
  gemm_k<3, 0, false, true, true, false, false, false><<<dim3(GX_ONEW, 3), blk512, 0, stream>>>(
      h1b3, SZ_BF, nullptr, 0, Wp2p, nullptr, bp2, scsh3, m2_3, SZ_BF, nullptr, nullptr, NNODES);
  agg_k<<<dim3(aggGrid, 3), blk, 0, stream>>>((const unsigned short*)m2_3,
                                              (long)NNODES * FD, ssrc3, offs3,
                                              (unsigned short*)aggb3);
  // out[g] = bnrelu(h1[g])@Ws2^T + agg2[g]@Wn2^T + b2 -> d_out (f32, NT stores)
  gemm_k<3, 1, true, false, false, false, false, true><<<dim3(GX_TWOA, 3), blk512, 0, stream>>>(
      h1b3, SZ_BF, aggb3, SZ_BF, Ws2p, Wn2p, b2, scsh3, d_out, SZ_F32, nullptr, nullptr, NNODES);
}